// Round 4
// baseline (952.490 us; speedup 1.0000x reference)
//
#include <hip/hip_runtime.h>

// Problem constants (fixed by the reference)
#define B_    128
#define L_    1024
#define DK_   128
#define DV_   256
#define NS_   50      // N memory slots
#define H_    256
#define M_    (B_ * L_)   // 131072 rows

typedef __attribute__((ext_vector_type(8))) short   short8;
typedef __attribute__((ext_vector_type(4))) float   float4v;
typedef __attribute__((ext_vector_type(2))) float   float2v;
typedef __attribute__((ext_vector_type(4))) int     int4v;

__device__ __forceinline__ float b2f(unsigned short u) {
    unsigned int x = ((unsigned int)u) << 16;
    return __builtin_bit_cast(float, x);
}
__device__ __forceinline__ unsigned short f2b(float f) {
    unsigned int x = __builtin_bit_cast(unsigned int, f);
    x += 0x7fffu + ((x >> 16) & 1u);   // round-to-nearest-even
    return (unsigned short)(x >> 16);
}
__device__ __forceinline__ int pack2(float lo, float hi) {
    return (int)f2b(lo) | ((int)f2b(hi) << 16);
}
__device__ __forceinline__ float sigmoid_f(float x) {
    return 1.f / (1.f + __expf(-x));
}
__device__ __forceinline__ float tanh_f(float x) {
    return 1.f - 2.f / (__expf(2.f * x) + 1.f);  // safe at exp overflow
}

// ---------------------------------------------------------------------------
// Gate kernel: e = sigmoid(X We^T + be), a = tanh(X Wa^T + ba)
// X: (M_,256) fp32. We/Wa: (256,256) fp32 row-major [out][in] = B^T layout.
// Outputs bf16. grid (M_/128, 2, 2)  block 256
// ---------------------------------------------------------------------------
__global__ __launch_bounds__(256) void gate_kernel(
    const float* __restrict__ X,
    const float* __restrict__ We, const float* __restrict__ be,
    const float* __restrict__ Wa, const float* __restrict__ ba,
    unsigned short* __restrict__ e_out, unsigned short* __restrict__ a_out)
{
    constexpr int K = DV_;  // 256
    const int mblk = blockIdx.x, nblk = blockIdx.y, gate = blockIdx.z;
    const float* W    = gate ? Wa : We;
    const float* bias = gate ? ba : be;
    unsigned short* out = gate ? a_out : e_out;

    __shared__ unsigned short As[128 * 40];  // +8 pad per row
    __shared__ unsigned short Bs[128 * 40];

    const int tid  = threadIdx.x;
    const int lane = tid & 63, wid = tid >> 6;
    const int wm = wid >> 1, wn = wid & 1;
    const int l15 = lane & 15, quad = lane >> 4;

    float4v acc[4][4];
#pragma unroll
    for (int i = 0; i < 4; i++)
#pragma unroll
        for (int j = 0; j < 4; j++) {
            acc[i][j][0] = 0.f; acc[i][j][1] = 0.f;
            acc[i][j][2] = 0.f; acc[i][j][3] = 0.f;
        }

    const int srow = tid >> 1;          // 0..127
    const int scol = (tid & 1) * 16;    // 0 or 16 (bf16 element units)
    const size_t Abase = ((size_t)mblk * 128 + srow) * K;
    const size_t Bbase = ((size_t)nblk * 128 + srow) * K;

    for (int k0 = 0; k0 < K; k0 += 32) {
        const float* xa = &X[Abase + k0 + scol];
        const float* xb = &W[Bbase + k0 + scol];
        // vectorized fp32 loads (dwordx4), then pack to bf16
        float4v va0 = *(const float4v*)(xa);
        float4v va1 = *(const float4v*)(xa + 4);
        float4v va2 = *(const float4v*)(xa + 8);
        float4v va3 = *(const float4v*)(xa + 12);
        float4v vb0 = *(const float4v*)(xb);
        float4v vb1 = *(const float4v*)(xb + 4);
        float4v vb2 = *(const float4v*)(xb + 8);
        float4v vb3 = *(const float4v*)(xb + 12);
        int4v pa0, pa1, pb0, pb1;
        pa0[0] = pack2(va0[0], va0[1]); pa0[1] = pack2(va0[2], va0[3]);
        pa0[2] = pack2(va1[0], va1[1]); pa0[3] = pack2(va1[2], va1[3]);
        pa1[0] = pack2(va2[0], va2[1]); pa1[1] = pack2(va2[2], va2[3]);
        pa1[2] = pack2(va3[0], va3[1]); pa1[3] = pack2(va3[2], va3[3]);
        pb0[0] = pack2(vb0[0], vb0[1]); pb0[1] = pack2(vb0[2], vb0[3]);
        pb0[2] = pack2(vb1[0], vb1[1]); pb0[3] = pack2(vb1[2], vb1[3]);
        pb1[0] = pack2(vb2[0], vb2[1]); pb1[1] = pack2(vb2[2], vb2[3]);
        pb1[2] = pack2(vb3[0], vb3[1]); pb1[3] = pack2(vb3[2], vb3[3]);
        *(int4v*)&As[srow * 40 + scol]     = pa0;
        *(int4v*)&As[srow * 40 + scol + 8] = pa1;
        *(int4v*)&Bs[srow * 40 + scol]     = pb0;
        *(int4v*)&Bs[srow * 40 + scol + 8] = pb1;
        __syncthreads();
        short8 af[4], bf[4];
#pragma unroll
        for (int i = 0; i < 4; i++)
            af[i] = *(const short8*)&As[(64 * wm + 16 * i + l15) * 40 + quad * 8];
#pragma unroll
        for (int j = 0; j < 4; j++)
            bf[j] = *(const short8*)&Bs[(64 * wn + 16 * j + l15) * 40 + quad * 8];
#pragma unroll
        for (int i = 0; i < 4; i++)
#pragma unroll
            for (int j = 0; j < 4; j++)
                acc[i][j] = __builtin_amdgcn_mfma_f32_16x16x32_bf16(af[i], bf[j], acc[i][j], 0, 0, 0);
        __syncthreads();
    }

#pragma unroll
    for (int i = 0; i < 4; i++) {
        const int row = mblk * 128 + 64 * wm + 16 * i + quad * 4;
#pragma unroll
        for (int j = 0; j < 4; j++) {
            const int col = nblk * 128 + 64 * wn + 16 * j + l15;
            const float bv = bias[col];
#pragma unroll
            for (int r = 0; r < 4; r++) {
                float v = acc[i][j][r] + bv;
                v = gate ? tanh_f(v) : sigmoid_f(v);
                out[(size_t)(row + r) * DV_ + col] = f2b(v);
            }
        }
    }
}

// ---------------------------------------------------------------------------
// Score kernel: score = softmax(P Wk^T) over 50 slots. Thread per row. fp32.
// Direct layout: (M_,64) fp32, column n = softmax slot n for n<50, 0 else.
// grid 512, block 256
// ---------------------------------------------------------------------------
__global__ __launch_bounds__(256) void score_kernel(
    const float* __restrict__ problems,  // (M_,128)
    const float* __restrict__ w_key,     // (50,128)
    float* __restrict__ score_scan)      // (M_,64)
{
    const int rowi = blockIdx.x * 256 + threadIdx.x;
    const float* p = problems + (size_t)rowi * DK_;

    float logit[NS_];
#pragma unroll
    for (int n = 0; n < NS_; n++) logit[n] = 0.f;

    for (int k0 = 0; k0 < DK_; k0 += 4) {
        float pf0 = p[k0], pf1 = p[k0+1], pf2 = p[k0+2], pf3 = p[k0+3];
#pragma unroll
        for (int n = 0; n < NS_; n++) {
            const float* wk = &w_key[n * DK_ + k0];   // wave-uniform -> s_load
            logit[n] += pf0 * wk[0] + pf1 * wk[1] + pf2 * wk[2] + pf3 * wk[3];
        }
    }

    float mx = logit[0];
#pragma unroll
    for (int n = 1; n < NS_; n++) mx = fmaxf(mx, logit[n]);
    float sum = 0.f;
#pragma unroll
    for (int n = 0; n < NS_; n++) { logit[n] = __expf(logit[n] - mx); sum += logit[n]; }
    const float inv = 1.f / sum;

    float* o = score_scan + (size_t)rowi * 64;
#pragma unroll
    for (int v = 0; v < 16; v++) {
        float4v st;
#pragma unroll
        for (int c = 0; c < 4; c++) {
            const int j = v * 4 + c;
            st[c] = (j < NS_) ? logit[j] * inv : 0.f;
        }
        *(float4v*)(o + v * 4) = st;
    }
}

// ---------------------------------------------------------------------------
// Scan kernel v6: 512-thread blocks (8 waves), wave w owns slots 8w..8w+7
// (direct score layout, slots 50..63 zero -> zero contribution). All 64 lanes
// of a wave = 64 d-columns. No LDS staging: deep register pipelines
// (e/a depth-8 ushort, s depth-4 x8 floats, statically indexed via full
// 16-unroll). LDS holds only the cross-wave partial buffer r_s[8][16][64]
// (32 KB), reduced + stored every 16 t.
// 2 blocks/CU -> 16 waves/CU = 4 waves/SIMD.
// grid (4, 128)  block 512.
// NOTE: depth-8 prefetch overreads up to 8 rows past each buffer; workspace
// is ordered e | a | score | reads so overreads stay inside the workspace.
// ---------------------------------------------------------------------------
#define RCH 16           // reduce subchunk (t per barrier period)

__global__ __launch_bounds__(512, 4) void scan_kernel(
    const float* __restrict__ score_scan,         // (M_,64) fp32, direct+padded
    const unsigned short* __restrict__ e_buf,     // (M_,256) bf16
    const unsigned short* __restrict__ a_buf,     // (M_,256) bf16
    const float* __restrict__ init_mem,           // (50,256) fp32
    unsigned short* __restrict__ reads)           // (M_,256) bf16
{
    __shared__ float r_s[8][RCH][64];   // 32 KB

    const int b    = blockIdx.y;
    const int dblk = blockIdx.x;          // 0..3
    const int tid  = threadIdx.x;
    const int w    = tid >> 6;            // wave id = slot group 0..7
    const int lane = tid & 63;            // d sub-index
    const int d    = dblk * 64 + lane;

    float M[8];
#pragma unroll
    for (int i = 0; i < 8; i++) {
        const int n = w * 8 + i;
        M[i] = (n < NS_) ? init_mem[n * DV_ + d] : 0.f;
    }

    const size_t rb = (size_t)b * L_;
    const float* sbase = score_scan + rb * 64 + w * 8;   // wave-uniform
    const unsigned short* ep = e_buf + rb * DV_ + d;
    const unsigned short* ap = a_buf + rb * DV_ + d;

    // register pipelines
    float s_p[4][8];                 // s, depth 4
    unsigned short e_p[8], a_p[8];   // e/a raw bf16, depth 8

#pragma unroll
    for (int k = 0; k < 4; k++) {
        const float* sp = sbase + (size_t)k * 64;
        float4v x0 = *(const float4v*)(sp);
        float4v x1 = *(const float4v*)(sp + 4);
        s_p[k][0] = x0[0]; s_p[k][1] = x0[1]; s_p[k][2] = x0[2]; s_p[k][3] = x0[3];
        s_p[k][4] = x1[0]; s_p[k][5] = x1[1]; s_p[k][6] = x1[2]; s_p[k][7] = x1[3];
    }
#pragma unroll
    for (int k = 0; k < 8; k++) {
        e_p[k] = ep[(size_t)k * DV_];
        a_p[k] = ap[(size_t)k * DV_];
    }

    for (int t0 = 0; t0 < L_; t0 += RCH) {
#pragma unroll
        for (int u = 0; u < RCH; u++) {
            const float e_cur = b2f(e_p[u & 7]);
            const float a_cur = b2f(a_p[u & 7]);
            float r = 0.f;
#pragma unroll
            for (int i = 0; i < 8; i++) {
                const float s = s_p[u & 3][i];
                r = fmaf(s, M[i], r);                       // read BEFORE update
                M[i] = fmaf(s, fmaf(-e_cur, M[i], a_cur), M[i]);
            }
            r_s[w][u][lane] = r;
            // refills (unclamped; overreads stay inside workspace)
            {
                const float* sp = sbase + (size_t)(t0 + u + 4) * 64;
                float4v x0 = *(const float4v*)(sp);
                float4v x1 = *(const float4v*)(sp + 4);
                s_p[u & 3][0] = x0[0]; s_p[u & 3][1] = x0[1];
                s_p[u & 3][2] = x0[2]; s_p[u & 3][3] = x0[3];
                s_p[u & 3][4] = x1[0]; s_p[u & 3][5] = x1[1];
                s_p[u & 3][6] = x1[2]; s_p[u & 3][7] = x1[3];
            }
            e_p[u & 7] = ep[(size_t)(t0 + u + 8) * DV_];
            a_p[u & 7] = ap[(size_t)(t0 + u + 8) * DV_];
        }

        __syncthreads();
        {   // reduce partials across the 8 waves, store RCH t of reads
            const int tt = tid >> 5;          // 0..15
            const int d0 = (tid & 31) * 2;    // 0,2,...,62
            float2v sm = *(const float2v*)&r_s[0][tt][d0];
#pragma unroll
            for (int ww = 1; ww < 8; ww++) {
                float2v v = *(const float2v*)&r_s[ww][tt][d0];
                sm[0] += v[0]; sm[1] += v[1];
            }
            *(unsigned int*)&reads[(rb + t0 + tt) * (size_t)DV_ + dblk * 64 + d0] =
                (unsigned int)pack2(sm[0], sm[1]);
        }
        __syncthreads();   // r_s free for next subchunk
    }
}

// ---------------------------------------------------------------------------
// Output kernel: out = tanh([reads | problems] Wo^T + bo), fp32 out
// K = 384 (256 reads bf16 + 128 problems fp32). grid (M_/128, 2) block 256
// ---------------------------------------------------------------------------
__global__ __launch_bounds__(256) void out_kernel(
    const unsigned short* __restrict__ reads,  // (M_,256) bf16
    const float* __restrict__ problems,        // (M_,128) fp32
    const float* __restrict__ Wo,              // (256,384) fp32
    const float* __restrict__ bo,              // (256) fp32
    float* __restrict__ out)                   // (M_,256) fp32
{
    constexpr int K = DV_ + DK_;  // 384
    const int mblk = blockIdx.x, nblk = blockIdx.y;

    __shared__ unsigned short As[128 * 40];
    __shared__ unsigned short Bs[128 * 40];

    const int tid  = threadIdx.x;
    const int lane = tid & 63, wid = tid >> 6;
    const int wm = wid >> 1, wn = wid & 1;
    const int l15 = lane & 15, quad = lane >> 4;

    float4v acc[4][4];
#pragma unroll
    for (int i = 0; i < 4; i++)
#pragma unroll
        for (int j = 0; j < 4; j++) {
            acc[i][j][0] = 0.f; acc[i][j][1] = 0.f;
            acc[i][j][2] = 0.f; acc[i][j][3] = 0.f;
        }

    const int srow = tid >> 1;
    const int scol = (tid & 1) * 16;
    const size_t mrow = (size_t)mblk * 128 + srow;
    const size_t brow = (size_t)nblk * 128 + srow;

    for (int k0 = 0; k0 < K; k0 += 32) {
        const int kk = k0 + scol;
        int4v a0, a1;
        if (kk < DV_) {  // reads, already bf16
            a0 = *(const int4v*)&reads[mrow * DV_ + kk];
            a1 = *(const int4v*)&reads[mrow * DV_ + kk + 8];
        } else {         // problems, fp32 -> bf16 (vectorized loads)
            const float* pr = &problems[mrow * DK_ + (kk - DV_)];
            float4v v0 = *(const float4v*)(pr);
            float4v v1 = *(const float4v*)(pr + 4);
            float4v v2 = *(const float4v*)(pr + 8);
            float4v v3 = *(const float4v*)(pr + 12);
            a0[0] = pack2(v0[0], v0[1]); a0[1] = pack2(v0[2], v0[3]);
            a0[2] = pack2(v1[0], v1[1]); a0[3] = pack2(v1[2], v1[3]);
            a1[0] = pack2(v2[0], v2[1]); a1[1] = pack2(v2[2], v2[3]);
            a1[2] = pack2(v3[0], v3[1]); a1[3] = pack2(v3[2], v3[3]);
        }
        const float* wb = &Wo[brow * K + kk];
        float4v u0 = *(const float4v*)(wb);
        float4v u1 = *(const float4v*)(wb + 4);
        float4v u2 = *(const float4v*)(wb + 8);
        float4v u3 = *(const float4v*)(wb + 12);
        int4v b0, b1;
        b0[0] = pack2(u0[0], u0[1]); b0[1] = pack2(u0[2], u0[3]);
        b0[2] = pack2(u1[0], u1[1]); b0[3] = pack2(u1[2], u1[3]);
        b1[0] = pack2(u2[0], u2[1]); b1[1] = pack2(u2[2], u2[3]);
        b1[2] = pack2(u3[0], u3[1]); b1[3] = pack2(u3[2], u3[3]);
        *(int4v*)&As[srow * 40 + scol]     = a0;
        *(int4v*)&As[srow * 40 + scol + 8] = a1;
        *(int4v*)&Bs[srow * 40 + scol]     = b0;
        *(int4v*)&Bs[srow * 40 + scol + 8] = b1;
        __syncthreads();
        short8 af[4], bf[4];
#pragma unroll
        for (int i = 0; i < 4; i++)
            af[i] = *(const short8*)&As[(64 * wm + 16 * i + l15) * 40 + quad * 8];
#pragma unroll
        for (int j = 0; j < 4; j++)
            bf[j] = *(const short8*)&Bs[(64 * wn + 16 * j + l15) * 40 + quad * 8];
#pragma unroll
        for (int i = 0; i < 4; i++)
#pragma unroll
            for (int j = 0; j < 4; j++)
                acc[i][j] = __builtin_amdgcn_mfma_f32_16x16x32_bf16(af[i], bf[j], acc[i][j], 0, 0, 0);
        __syncthreads();
    }

#pragma unroll
    for (int i = 0; i < 4; i++) {
        const int row = mblk * 128 + 64 * wm + 16 * i + quad * 4;
#pragma unroll
        for (int j = 0; j < 4; j++) {
            const int col = nblk * 128 + 64 * wn + 16 * j + l15;
            const float bv = bo[col];
#pragma unroll
            for (int r = 0; r < 4; r++) {
                out[(size_t)(row + r) * H_ + col] = tanh_f(acc[i][j][r] + bv);
            }
        }
    }
}

// ---------------------------------------------------------------------------
extern "C" void kernel_launch(void* const* d_in, const int* in_sizes, int n_in,
                              void* d_out, int out_size, void* d_ws, size_t ws_size,
                              hipStream_t stream) {
    const float* problems  = (const float*)d_in[0];
    const float* interact  = (const float*)d_in[1];
    const float* w_key     = (const float*)d_in[2];
    const float* w_erase_w = (const float*)d_in[3];
    const float* w_erase_b = (const float*)d_in[4];
    const float* w_add_w   = (const float*)d_in[5];
    const float* w_add_b   = (const float*)d_in[6];
    const float* w_out_w   = (const float*)d_in[7];
    const float* w_out_b   = (const float*)d_in[8];
    const float* init_mem  = (const float*)d_in[9];

    // workspace: e (64MB bf16) | a (64MB bf16) | score_scan (32MB fp32) | reads (64MB bf16)
    // (reads last so the scan's depth-8 prefetch overreads of e/a/score stay
    //  inside the workspace)
    char* ws = (char*)d_ws;
    const size_t SZ_BF = (size_t)M_ * DV_ * 2;   // 67,108,864
    const size_t SZ_SC = (size_t)M_ * 64 * 4;    // 33,554,432
    unsigned short* e_buf = (unsigned short*)(ws);
    unsigned short* a_buf = (unsigned short*)(ws + SZ_BF);
    float*     score_scan = (float*)(ws + 2 * SZ_BF);
    unsigned short* reads = (unsigned short*)(ws + 2 * SZ_BF + SZ_SC);

    gate_kernel<<<dim3(M_ / 128, DV_ / 128, 2), 256, 0, stream>>>(
        interact, w_erase_w, w_erase_b, w_add_w, w_add_b, e_buf, a_buf);

    score_kernel<<<M_ / 256, 256, 0, stream>>>(problems, w_key, score_scan);

    scan_kernel<<<dim3(4, B_), 512, 0, stream>>>(
        score_scan, e_buf, a_buf, init_mem, reads);

    out_kernel<<<dim3(M_ / 128, H_ / 128), 256, 0, stream>>>(
        reads, problems, w_out_w, w_out_b, (float*)d_out);
}

// Round 6
// 832.240 us; speedup vs baseline: 1.1445x; 1.1445x over previous
//
#include <hip/hip_runtime.h>

// Problem constants (fixed by the reference)
#define B_    128
#define L_    1024
#define DK_   128
#define DV_   256
#define NS_   50      // N memory slots
#define H_    256
#define M_    (B_ * L_)   // 131072 rows

typedef __attribute__((ext_vector_type(8))) short   short8;
typedef __attribute__((ext_vector_type(4))) float   float4v;
typedef __attribute__((ext_vector_type(2))) float   float2v;
typedef __attribute__((ext_vector_type(4))) int     int4v;

__device__ __forceinline__ float b2f(unsigned short u) {
    unsigned int x = ((unsigned int)u) << 16;
    return __builtin_bit_cast(float, x);
}
__device__ __forceinline__ unsigned short f2b(float f) {
    unsigned int x = __builtin_bit_cast(unsigned int, f);
    x += 0x7fffu + ((x >> 16) & 1u);   // round-to-nearest-even
    return (unsigned short)(x >> 16);
}
__device__ __forceinline__ int pack2(float lo, float hi) {
    return (int)f2b(lo) | ((int)f2b(hi) << 16);
}
__device__ __forceinline__ float sigmoid_f(float x) {
    return 1.f / (1.f + __expf(-x));
}
__device__ __forceinline__ float tanh_f(float x) {
    return 1.f - 2.f / (__expf(2.f * x) + 1.f);  // safe at exp overflow
}

// async global -> LDS, 16B per lane (wave-uniform LDS base; HW adds lane*16)
__device__ __forceinline__ void gload_lds16(const void* g, void* l) {
    __builtin_amdgcn_global_load_lds(
        (const __attribute__((address_space(1))) void*)g,
        (__attribute__((address_space(3))) void*)l, 16, 0, 0);
}

// ---------------------------------------------------------------------------
// Fused gate kernel: e = sigmoid(X We^T + be), a = tanh(X Wa^T + ba)
// X staged/packed ONCE for both gates. Outputs separate bf16 buffers
// (workspace layout identical to the verified 225.5MB footprint).
// grid (M_/128, 2)  block 256
// ---------------------------------------------------------------------------
__global__ __launch_bounds__(256) void gate_kernel(
    const float* __restrict__ X,
    const float* __restrict__ We, const float* __restrict__ be,
    const float* __restrict__ Wa, const float* __restrict__ ba,
    unsigned short* __restrict__ e_out, unsigned short* __restrict__ a_out)
{
    constexpr int K = DV_;  // 256
    const int mblk = blockIdx.x, nblk = blockIdx.y;

    __shared__ unsigned short As[128 * 40];  // +8 pad per row
    __shared__ unsigned short Be[128 * 40];
    __shared__ unsigned short Ba[128 * 40];

    const int tid  = threadIdx.x;
    const int lane = tid & 63, wid = tid >> 6;
    const int wm = wid >> 1, wn = wid & 1;
    const int l15 = lane & 15, quad = lane >> 4;

    float4v acce[4][4], acca[4][4];
#pragma unroll
    for (int i = 0; i < 4; i++)
#pragma unroll
        for (int j = 0; j < 4; j++) {
            acce[i][j][0] = 0.f; acce[i][j][1] = 0.f;
            acce[i][j][2] = 0.f; acce[i][j][3] = 0.f;
            acca[i][j][0] = 0.f; acca[i][j][1] = 0.f;
            acca[i][j][2] = 0.f; acca[i][j][3] = 0.f;
        }

    const int srow = tid >> 1;          // 0..127
    const int scol = (tid & 1) * 16;    // 0 or 16 (bf16 element units)
    const size_t Abase = ((size_t)mblk * 128 + srow) * K;
    const size_t Bbase = ((size_t)nblk * 128 + srow) * K;

    for (int k0 = 0; k0 < K; k0 += 32) {
        {   // A: X fp32 -> bf16, staged once for both gates
            const float* xa = &X[Abase + k0 + scol];
            float4v v0 = *(const float4v*)(xa);
            float4v v1 = *(const float4v*)(xa + 4);
            float4v v2 = *(const float4v*)(xa + 8);
            float4v v3 = *(const float4v*)(xa + 12);
            int4v p0, p1;
            p0[0] = pack2(v0[0], v0[1]); p0[1] = pack2(v0[2], v0[3]);
            p0[2] = pack2(v1[0], v1[1]); p0[3] = pack2(v1[2], v1[3]);
            p1[0] = pack2(v2[0], v2[1]); p1[1] = pack2(v2[2], v2[3]);
            p1[2] = pack2(v3[0], v3[1]); p1[3] = pack2(v3[2], v3[3]);
            *(int4v*)&As[srow * 40 + scol]     = p0;
            *(int4v*)&As[srow * 40 + scol + 8] = p1;
        }
        {   // We tile
            const float* wb = &We[Bbase + k0 + scol];
            float4v v0 = *(const float4v*)(wb);
            float4v v1 = *(const float4v*)(wb + 4);
            float4v v2 = *(const float4v*)(wb + 8);
            float4v v3 = *(const float4v*)(wb + 12);
            int4v p0, p1;
            p0[0] = pack2(v0[0], v0[1]); p0[1] = pack2(v0[2], v0[3]);
            p0[2] = pack2(v1[0], v1[1]); p0[3] = pack2(v1[2], v1[3]);
            p1[0] = pack2(v2[0], v2[1]); p1[1] = pack2(v2[2], v2[3]);
            p1[2] = pack2(v3[0], v3[1]); p1[3] = pack2(v3[2], v3[3]);
            *(int4v*)&Be[srow * 40 + scol]     = p0;
            *(int4v*)&Be[srow * 40 + scol + 8] = p1;
        }
        {   // Wa tile
            const float* wb = &Wa[Bbase + k0 + scol];
            float4v v0 = *(const float4v*)(wb);
            float4v v1 = *(const float4v*)(wb + 4);
            float4v v2 = *(const float4v*)(wb + 8);
            float4v v3 = *(const float4v*)(wb + 12);
            int4v p0, p1;
            p0[0] = pack2(v0[0], v0[1]); p0[1] = pack2(v0[2], v0[3]);
            p0[2] = pack2(v1[0], v1[1]); p0[3] = pack2(v1[2], v1[3]);
            p1[0] = pack2(v2[0], v2[1]); p1[1] = pack2(v2[2], v2[3]);
            p1[2] = pack2(v3[0], v3[1]); p1[3] = pack2(v3[2], v3[3]);
            *(int4v*)&Ba[srow * 40 + scol]     = p0;
            *(int4v*)&Ba[srow * 40 + scol + 8] = p1;
        }
        __syncthreads();
        short8 af[4];
#pragma unroll
        for (int i = 0; i < 4; i++)
            af[i] = *(const short8*)&As[(64 * wm + 16 * i + l15) * 40 + quad * 8];
        {   // e gate MFMAs
            short8 bf[4];
#pragma unroll
            for (int j = 0; j < 4; j++)
                bf[j] = *(const short8*)&Be[(64 * wn + 16 * j + l15) * 40 + quad * 8];
#pragma unroll
            for (int i = 0; i < 4; i++)
#pragma unroll
                for (int j = 0; j < 4; j++)
                    acce[i][j] = __builtin_amdgcn_mfma_f32_16x16x32_bf16(af[i], bf[j], acce[i][j], 0, 0, 0);
        }
        {   // a gate MFMAs
            short8 bf[4];
#pragma unroll
            for (int j = 0; j < 4; j++)
                bf[j] = *(const short8*)&Ba[(64 * wn + 16 * j + l15) * 40 + quad * 8];
#pragma unroll
            for (int i = 0; i < 4; i++)
#pragma unroll
                for (int j = 0; j < 4; j++)
                    acca[i][j] = __builtin_amdgcn_mfma_f32_16x16x32_bf16(af[i], bf[j], acca[i][j], 0, 0, 0);
        }
        __syncthreads();
    }

#pragma unroll
    for (int i = 0; i < 4; i++) {
        const int row = mblk * 128 + 64 * wm + 16 * i + quad * 4;
#pragma unroll
        for (int j = 0; j < 4; j++) {
            const int col = nblk * 128 + 64 * wn + 16 * j + l15;
            const float bve = be[col];
            const float bva = ba[col];
#pragma unroll
            for (int r = 0; r < 4; r++) {
                e_out[(size_t)(row + r) * DV_ + col] = f2b(sigmoid_f(acce[i][j][r] + bve));
                a_out[(size_t)(row + r) * DV_ + col] = f2b(tanh_f(acca[i][j][r] + bva));
            }
        }
    }
}

// ---------------------------------------------------------------------------
// Score kernel: score = softmax(P Wk^T) over 50 slots. Thread per row. fp32.
// Direct layout: (M_,64) fp32, column n = softmax slot n for n<50, 0 else.
// grid 512, block 256
// ---------------------------------------------------------------------------
__global__ __launch_bounds__(256) void score_kernel(
    const float* __restrict__ problems,  // (M_,128)
    const float* __restrict__ w_key,     // (50,128)
    float* __restrict__ score_scan)      // (M_,64)
{
    const int rowi = blockIdx.x * 256 + threadIdx.x;
    const float* p = problems + (size_t)rowi * DK_;

    float logit[NS_];
#pragma unroll
    for (int n = 0; n < NS_; n++) logit[n] = 0.f;

    for (int k0 = 0; k0 < DK_; k0 += 4) {
        float pf0 = p[k0], pf1 = p[k0+1], pf2 = p[k0+2], pf3 = p[k0+3];
#pragma unroll
        for (int n = 0; n < NS_; n++) {
            const float* wk = &w_key[n * DK_ + k0];   // wave-uniform -> s_load
            logit[n] += pf0 * wk[0] + pf1 * wk[1] + pf2 * wk[2] + pf3 * wk[3];
        }
    }

    float mx = logit[0];
#pragma unroll
    for (int n = 1; n < NS_; n++) mx = fmaxf(mx, logit[n]);
    float sum = 0.f;
#pragma unroll
    for (int n = 0; n < NS_; n++) { logit[n] = __expf(logit[n] - mx); sum += logit[n]; }
    const float inv = 1.f / sum;

    float* o = score_scan + (size_t)rowi * 64;
#pragma unroll
    for (int v = 0; v < 16; v++) {
        float4v st;
#pragma unroll
        for (int c = 0; c < 4; c++) {
            const int j = v * 4 + c;
            st[c] = (j < NS_) ? logit[j] * inv : 0.f;
        }
        *(float4v*)(o + v * 4) = st;
    }
}

// ---------------------------------------------------------------------------
// Scan kernel v7b: 512-thread blocks, 8 waves; wave w owns slots 8w..8w+7
// (direct score layout, slots >=50 are zero -> contribute nothing). All 64
// lanes of a wave = 64 d-columns. s is wave-uniform (readfirstlane-forced
// SGPR base -> scalar loads, SMEM pipe), depth-2 pipeline. e/a bf16 staged
// via global_load_lds double-buffered (1 inst each per wave per chunk).
// Cross-wave partial reads via r_s LDS buffer, reduced+stored every 16 t.
// LDS: e/a 2x8KB each + r_s 32KB = 64KB -> 2 blocks/CU = 16 waves/CU = 4/SIMD.
// grid (4, 128)  block 512.
// ---------------------------------------------------------------------------
#define TCH 64           // staged timesteps per chunk
#define NCH (L_ / TCH)   // 16
#define RCH 16           // reduce subchunk

__global__ __launch_bounds__(512, 4) void scan_kernel(
    const float* __restrict__ score_scan,         // (M_,64) fp32, direct+padded
    const unsigned short* __restrict__ e_buf,     // (M_,256) bf16
    const unsigned short* __restrict__ a_buf,     // (M_,256) bf16
    const float* __restrict__ init_mem,           // (50,256) fp32
    unsigned short* __restrict__ reads)           // (M_,256) bf16
{
    __shared__ unsigned short e_s[2][TCH][64];   // 2 x 8 KB
    __shared__ unsigned short a_s[2][TCH][64];   // 2 x 8 KB
    __shared__ float          r_s[8][RCH][64];   // 32 KB

    const int b    = blockIdx.y;
    const int dblk = blockIdx.x;          // 0..3
    const int tid  = threadIdx.x;
    const int w    = tid >> 6;            // wave id = slot group 0..7
    const int wu   = __builtin_amdgcn_readfirstlane(w);  // provably uniform
    const int lane = tid & 63;            // d sub-index
    const int d    = dblk * 64 + lane;

    float M[8];
#pragma unroll
    for (int i = 0; i < 8; i++) {
        const int n = wu * 8 + i;
        M[i] = (n < NS_) ? init_mem[n * DV_ + d] : 0.f;
    }

    const size_t rb = (size_t)b * L_;
    const float* sbase = score_scan + rb * 64 + wu * 8;  // wave-uniform

    auto stage = [&](int c, int p) {
        // each wave stages its 8-row stripe of the 64-row chunk, e and a
        const int tt = c * TCH + wu * 8 + (lane >> 3);
        const size_t goff = (rb + tt) * (size_t)DV_ + dblk * 64 + (lane & 7) * 8;
        gload_lds16(e_buf + goff, &e_s[p][wu * 8][0]);
        gload_lds16(a_buf + goff, &a_s[p][wu * 8][0]);
    };

    float sc[8], sn[8];
#define LOADS(dst, t) { \
        const float* sp_ = sbase + (size_t)(t) * 64; \
        const float4v x0_ = *(const float4v*)(sp_); \
        const float4v x1_ = *(const float4v*)(sp_ + 4); \
        dst[0]=x0_[0]; dst[1]=x0_[1]; dst[2]=x0_[2]; dst[3]=x0_[3]; \
        dst[4]=x1_[0]; dst[5]=x1_[1]; dst[6]=x1_[2]; dst[7]=x1_[3]; }

    int pp = 0;
    stage(0, 0);
    LOADS(sc, 0);
    LOADS(sn, 1);
    asm volatile("s_waitcnt vmcnt(0)" ::: "memory");
    __syncthreads();

    for (int c = 0; c < NCH; ++c) {
        if (c + 1 < NCH) stage(c + 1, pp ^ 1);   // in flight during compute

        for (int sub = 0; sub < TCH / RCH; ++sub) {
            const int tb = c * TCH + sub * RCH;
            const int lb = sub * RCH;
#pragma unroll
            for (int u = 0; u < RCH; u += 2) {
                {   // t = tb + u  (uses sc)
                    const float e_cur = b2f(e_s[pp][lb + u][lane]);
                    const float a_cur = b2f(a_s[pp][lb + u][lane]);
                    float r = 0.f;
#pragma unroll
                    for (int i = 0; i < 8; i++) {
                        const float s = sc[i];
                        r = fmaf(s, M[i], r);                   // read BEFORE update
                        M[i] = fmaf(s, fmaf(-e_cur, M[i], a_cur), M[i]);
                    }
                    r_s[w][u][lane] = r;
                    // overread <=2 rows past score at the very end: lands in
                    // the reads buffer (score precedes reads in workspace)
                    LOADS(sc, tb + u + 2);
                }
                {   // t = tb + u + 1  (uses sn)
                    const float e_cur = b2f(e_s[pp][lb + u + 1][lane]);
                    const float a_cur = b2f(a_s[pp][lb + u + 1][lane]);
                    float r = 0.f;
#pragma unroll
                    for (int i = 0; i < 8; i++) {
                        const float s = sn[i];
                        r = fmaf(s, M[i], r);
                        M[i] = fmaf(s, fmaf(-e_cur, M[i], a_cur), M[i]);
                    }
                    r_s[w][u + 1][lane] = r;
                    LOADS(sn, tb + u + 3);
                }
            }
            __syncthreads();
            {   // reduce partials across the 8 waves, store RCH t of reads
                const int tt = tid >> 5;          // 0..15
                const int d0 = (tid & 31) * 2;    // 0,2,...,62
                float2v sm = *(const float2v*)&r_s[0][tt][d0];
#pragma unroll
                for (int ww = 1; ww < 8; ww++) {
                    float2v v = *(const float2v*)&r_s[ww][tt][d0];
                    sm[0] += v[0]; sm[1] += v[1];
                }
                *(unsigned int*)&reads[(rb + tb + tt) * (size_t)DV_ + dblk * 64 + d0] =
                    (unsigned int)pack2(sm[0], sm[1]);
            }
            __syncthreads();   // r_s free for next subchunk
        }

        asm volatile("s_waitcnt vmcnt(0)" ::: "memory");  // next chunk landed
        __syncthreads();
        pp ^= 1;
    }
#undef LOADS
}

// ---------------------------------------------------------------------------
// Output kernel: out = tanh([reads | problems] Wo^T + bo), fp32 out
// K = 384 (256 reads bf16 + 128 problems fp32). grid (M_/128, 2) block 256
// ---------------------------------------------------------------------------
__global__ __launch_bounds__(256) void out_kernel(
    const unsigned short* __restrict__ reads,  // (M_,256) bf16
    const float* __restrict__ problems,        // (M_,128) fp32
    const float* __restrict__ Wo,              // (256,384) fp32
    const float* __restrict__ bo,              // (256) fp32
    float* __restrict__ out)                   // (M_,256) fp32
{
    constexpr int K = DV_ + DK_;  // 384
    const int mblk = blockIdx.x, nblk = blockIdx.y;

    __shared__ unsigned short As[128 * 40];
    __shared__ unsigned short Bs[128 * 40];

    const int tid  = threadIdx.x;
    const int lane = tid & 63, wid = tid >> 6;
    const int wm = wid >> 1, wn = wid & 1;
    const int l15 = lane & 15, quad = lane >> 4;

    float4v acc[4][4];
#pragma unroll
    for (int i = 0; i < 4; i++)
#pragma unroll
        for (int j = 0; j < 4; j++) {
            acc[i][j][0] = 0.f; acc[i][j][1] = 0.f;
            acc[i][j][2] = 0.f; acc[i][j][3] = 0.f;
        }

    const int srow = tid >> 1;
    const int scol = (tid & 1) * 16;
    const size_t mrow = (size_t)mblk * 128 + srow;
    const size_t brow = (size_t)nblk * 128 + srow;

    for (int k0 = 0; k0 < K; k0 += 32) {
        const int kk = k0 + scol;
        int4v a0, a1;
        if (kk < DV_) {  // reads, already bf16
            a0 = *(const int4v*)&reads[mrow * DV_ + kk];
            a1 = *(const int4v*)&reads[mrow * DV_ + kk + 8];
        } else {         // problems, fp32 -> bf16 (vectorized loads)
            const float* pr = &problems[mrow * DK_ + (kk - DV_)];
            float4v v0 = *(const float4v*)(pr);
            float4v v1 = *(const float4v*)(pr + 4);
            float4v v2 = *(const float4v*)(pr + 8);
            float4v v3 = *(const float4v*)(pr + 12);
            a0[0] = pack2(v0[0], v0[1]); a0[1] = pack2(v0[2], v0[3]);
            a0[2] = pack2(v1[0], v1[1]); a0[3] = pack2(v1[2], v1[3]);
            a1[0] = pack2(v2[0], v2[1]); a1[1] = pack2(v2[2], v2[3]);
            a1[2] = pack2(v3[0], v3[1]); a1[3] = pack2(v3[2], v3[3]);
        }
        const float* wb = &Wo[brow * K + kk];
        float4v u0 = *(const float4v*)(wb);
        float4v u1 = *(const float4v*)(wb + 4);
        float4v u2 = *(const float4v*)(wb + 8);
        float4v u3 = *(const float4v*)(wb + 12);
        int4v b0, b1;
        b0[0] = pack2(u0[0], u0[1]); b0[1] = pack2(u0[2], u0[3]);
        b0[2] = pack2(u1[0], u1[1]); b0[3] = pack2(u1[2], u1[3]);
        b1[0] = pack2(u2[0], u2[1]); b1[1] = pack2(u2[2], u2[3]);
        b1[2] = pack2(u3[0], u3[1]); b1[3] = pack2(u3[2], u3[3]);
        *(int4v*)&As[srow * 40 + scol]     = a0;
        *(int4v*)&As[srow * 40 + scol + 8] = a1;
        *(int4v*)&Bs[srow * 40 + scol]     = b0;
        *(int4v*)&Bs[srow * 40 + scol + 8] = b1;
        __syncthreads();
        short8 af[4], bf[4];
#pragma unroll
        for (int i = 0; i < 4; i++)
            af[i] = *(const short8*)&As[(64 * wm + 16 * i + l15) * 40 + quad * 8];
#pragma unroll
        for (int j = 0; j < 4; j++)
            bf[j] = *(const short8*)&Bs[(64 * wn + 16 * j + l15) * 40 + quad * 8];
#pragma unroll
        for (int i = 0; i < 4; i++)
#pragma unroll
            for (int j = 0; j < 4; j++)
                acc[i][j] = __builtin_amdgcn_mfma_f32_16x16x32_bf16(af[i], bf[j], acc[i][j], 0, 0, 0);
        __syncthreads();
    }

#pragma unroll
    for (int i = 0; i < 4; i++) {
        const int row = mblk * 128 + 64 * wm + 16 * i + quad * 4;
#pragma unroll
        for (int j = 0; j < 4; j++) {
            const int col = nblk * 128 + 64 * wn + 16 * j + l15;
            const float bv = bo[col];
#pragma unroll
            for (int r = 0; r < 4; r++) {
                out[(size_t)(row + r) * H_ + col] = tanh_f(acc[i][j][r] + bv);
            }
        }
    }
}

// ---------------------------------------------------------------------------
extern "C" void kernel_launch(void* const* d_in, const int* in_sizes, int n_in,
                              void* d_out, int out_size, void* d_ws, size_t ws_size,
                              hipStream_t stream) {
    const float* problems  = (const float*)d_in[0];
    const float* interact  = (const float*)d_in[1];
    const float* w_key     = (const float*)d_in[2];
    const float* w_erase_w = (const float*)d_in[3];
    const float* w_erase_b = (const float*)d_in[4];
    const float* w_add_w   = (const float*)d_in[5];
    const float* w_add_b   = (const float*)d_in[6];
    const float* w_out_w   = (const float*)d_in[7];
    const float* w_out_b   = (const float*)d_in[8];
    const float* init_mem  = (const float*)d_in[9];

    // workspace: e (64MB bf16) | a (64MB bf16) | score_scan (33.5MB fp32) | reads (64MB bf16)
    // = 225.5 MB total, same as the previously verified footprint.
    // (score precedes reads so the scan's <=2-row s-pipeline overread is safe)
    char* ws = (char*)d_ws;
    const size_t SZ_BF = (size_t)M_ * DV_ * 2;   // 67,108,864
    const size_t SZ_SC = (size_t)M_ * 64 * 4;    // 33,554,432
    unsigned short* e_buf = (unsigned short*)(ws);
    unsigned short* a_buf = (unsigned short*)(ws + SZ_BF);
    float*     score_scan = (float*)(ws + 2 * SZ_BF);
    unsigned short* reads = (unsigned short*)(ws + 2 * SZ_BF + SZ_SC);

    gate_kernel<<<dim3(M_ / 128, DV_ / 128), 256, 0, stream>>>(
        interact, w_erase_w, w_erase_b, w_add_w, w_add_b, e_buf, a_buf);

    score_kernel<<<M_ / 256, 256, 0, stream>>>(problems, w_key, score_scan);

    scan_kernel<<<dim3(4, B_), 512, 0, stream>>>(
        score_scan, e_buf, a_buf, init_mem, reads);

    out_kernel<<<dim3(M_ / 128, H_ / 128), 256, 0, stream>>>(
        reads, problems, w_out_w, w_out_b, (float*)d_out);
}